// Round 7
// baseline (369.219 us; speedup 1.0000x reference)
//
#include <hip/hip_runtime.h>

// VQ-VAE VectorQuantizer: bf16 split-MFMA distance + exact fp32 fallback.
// z: (32,64,64,64) NCHW fp32; codebook: (1024,64) fp32.
// d_out: [0]=loss, [1..]=z_q (NCHW).
//
// R7 (from R6): break the 6-deep chained MFMA accumulator into THREE
// independent 2-deep chains (one per split term hh/lh/hl), summed in fp32 at
// min-track. R6 evidence: MfmaUtil 19% x 105us ~= the 25us total MFMA work,
// i.e. the matrix pipe was stalled on intra-wave acc dependency chains
// (6-deep x ~40cyc latency = ~25% duty), not on staging. Consecutive MFMAs
// are now independent -> 2 waves/SIMD can feed the pipe.

#define CB_N   1024
#define KDIM   64
#define HWD    4096
#define CHW    (KDIM * HWD)
#define NQ     131072
#define TOTALF 8388608.0f
#define TAU    2.5e-4f
#define FCAP   16384
#define CHUNK  128            // codes per LDS chunk
#define NCHUNK (CB_N / CHUNK)

typedef __attribute__((ext_vector_type(8))) short  short8;
typedef __attribute__((ext_vector_type(4))) float  f32x4;

__device__ __forceinline__ unsigned short bf16_rne(float f) {
    union { float f; unsigned u; } c; c.f = f;
    return (unsigned short)((c.u + 0x7FFFu + ((c.u >> 16) & 1u)) >> 16);
}
__device__ __forceinline__ float bf16_tof(unsigned short h) {
    union { unsigned u; float f; } c; c.u = ((unsigned)h) << 16; return c.f;
}

// async 16B/lane global->LDS copy (wave-uniform contiguous; m97 pattern)
__device__ __forceinline__ void gload_lds16(const void* g, void* l) {
    __builtin_amdgcn_global_load_lds(
        (const __attribute__((address_space(1))) unsigned int*)g,
        (__attribute__((address_space(3))) unsigned int*)l,
        16, 0, 0);
}

// ---------- ws layout (byte offsets) ----------
// 0: loss_acc  4: flag_cnt  8: done_cnt
// 128:    norms   f32[1024]
// 4224:   cbh_sw  u16[1024*64]   (XOR-swizzled rows)
// 135296: cbl_sw  u16[1024*64]
// 266368: flag_q i32[FCAP]  331904: flag_m1 f32[FCAP]  397440: flag_idx i32[FCAP]

// ---------------- prep: bf16 hi/lo split, swizzled rows, norms, counters ----
__global__ void vq_prep(const float* __restrict__ cb,
                        float* __restrict__ norms,
                        unsigned short* __restrict__ cbh,
                        unsigned short* __restrict__ cbl,
                        float* __restrict__ loss_acc,
                        int* __restrict__ flag_cnt,
                        int* __restrict__ done_cnt) {
    const int tid = blockIdx.x * 256 + threadIdx.x;
    if (tid == 0) *loss_acc = 0.0f;
    if (tid == 1) *flag_cnt = 0;
    if (tid == 2) *done_cnt = 0;
    const int j  = tid >> 2;
    const int s2 = tid & 3;

    const float4* r4 = (const float4*)(cb + (size_t)j * KDIM);
    float s_norm = 0.0f;
    #pragma unroll
    for (int seg8 = 0; seg8 < 2; ++seg8) {
        const int s = s2 * 2 + seg8;
        float4 v0 = r4[s * 2 + 0];
        float4 v1 = r4[s * 2 + 1];
        float e[8] = {v0.x, v0.y, v0.z, v0.w, v1.x, v1.y, v1.z, v1.w};
        unsigned hh[4], ll[4];
        #pragma unroll
        for (int c = 0; c < 8; ++c) {
            float x = e[c];
            s_norm = fmaf(x, x, s_norm);
            unsigned short h = bf16_rne(x);
            unsigned short l = bf16_rne(x - bf16_tof(h));
            if ((c & 1) == 0) { hh[c >> 1] = h; ll[c >> 1] = l; }
            else { hh[c >> 1] |= ((unsigned)h) << 16; ll[c >> 1] |= ((unsigned)l) << 16; }
        }
        const int p = (s + j) & 7;
        *(uint4*)(cbh + (size_t)j * KDIM + p * 8) = make_uint4(hh[0], hh[1], hh[2], hh[3]);
        *(uint4*)(cbl + (size_t)j * KDIM + p * 8) = make_uint4(ll[0], ll[1], ll[2], ll[3]);
    }
    s_norm += __shfl_xor(s_norm, 1, 64);
    s_norm += __shfl_xor(s_norm, 2, 64);
    if (s2 == 0) norms[j] = s_norm;
}

// ---------------- main ------------------------------------------------------
__global__ __launch_bounds__(256, 3) void vq_main(
        const float* __restrict__ z,
        const float* __restrict__ cb,
        const unsigned short* __restrict__ cbh,
        const unsigned short* __restrict__ cbl,
        const float* __restrict__ norms,
        float* __restrict__ out,
        float* __restrict__ loss_acc,
        int* __restrict__ flag_q,
        float* __restrict__ flag_m1,
        int* __restrict__ flag_idx,
        int* __restrict__ flag_cnt) {
    __shared__ float          norms_s[CB_N];            // 4 KB
    __shared__ unsigned short bh_s[CHUNK * KDIM];       // 16 KB
    __shared__ unsigned short bl_s[CHUNK * KDIM];       // 16 KB
    __shared__ float          zn_s[128];
    __shared__ int            idx_s[128];

    const int tid  = threadIdx.x;
    const int w    = tid >> 6;
    const int lane = tid & 63;
    const int quad = lane >> 4;
    const int l16  = lane & 15;
    const int qb   = blockIdx.x * 128;     // block's 128 queries (same batch b)
    const int b    = qb >> 12;
    const int hw0  = qb & 4095;
    const int ch0  = blockIdx.x & (NCHUNK - 1);   // de-phase chunk start

    // ---- stage all code norms into LDS
    *(float4*)(norms_s + tid * 4) = *(const float4*)(norms + tid * 4);

    // ---- stage A-frags: wave w owns queries [32w, 32w+32); 2 tiles of 16.
    const float* zbase = z + (size_t)b * CHW + hw0 + 32 * w;
    short8 ah[2][2], al[2][2];
    float znp[2] = {0.f, 0.f};
    #pragma unroll
    for (int t = 0; t < 2; ++t)
        #pragma unroll
        for (int ks = 0; ks < 2; ++ks)
            #pragma unroll
            for (int j = 0; j < 8; ++j) {
                float v = zbase[(size_t)(ks * 32 + quad * 8 + j) * HWD + t * 16 + l16];
                znp[t] = fmaf(v, v, znp[t]);
                float s = -2.0f * v;
                unsigned short h = bf16_rne(s);
                ah[t][ks][j] = (short)h;
                al[t][ks][j] = (short)bf16_rne(s - bf16_tof(h));
            }
    #pragma unroll
    for (int t = 0; t < 2; ++t) {
        znp[t] += __shfl_xor(znp[t], 16, 64);
        znp[t] += __shfl_xor(znp[t], 32, 64);
    }
    if (lane < 16) {
        zn_s[32 * w + lane]      = znp[0];
        zn_s[32 * w + 16 + lane] = znp[1];
    }

    // ---- chunk loop (round-robin from ch0): async-stage 128 codes, 8 n-tiles
    float m1[2][4], m2[2][4];
    int   i1[2][4];
    #pragma unroll
    for (int t = 0; t < 2; ++t)
        #pragma unroll
        for (int r = 0; r < 4; ++r) { m1[t][r] = 3.4e38f; m2[t][r] = 3.4e38f; i1[t][r] = 0; }

    for (int cc = 0; cc < NCHUNK; ++cc) {
        const int ch = (cc + ch0) & (NCHUNK - 1);
        if (cc) __syncthreads();           // previous chunk's LDS reads done
        {
            const char* gh = (const char*)cbh + (size_t)ch * CHUNK * KDIM * 2;
            const char* gl = (const char*)cbl + (size_t)ch * CHUNK * KDIM * 2;
            #pragma unroll
            for (int i = 0; i < 4; ++i) {
                const int off = (w * 4 + i) * 1024 + lane * 16;
                gload_lds16(gh + off, (char*)bh_s + off);
                gload_lds16(gl + off, (char*)bl_s + off);
            }
        }
        __syncthreads();                   // drains vmcnt -> LDS valid

        #pragma unroll
        for (int t8 = 0; t8 < 8; ++t8) {
            const int crow = t8 * 16 + l16;            // chunk-local code row
            const float nv = norms_s[ch * CHUNK + crow];
            const int p0 = ((quad + l16) & 7) * 8;     // swizzled seg, ks=0
            const int p1 = ((4 + quad + l16) & 7) * 8; // ks=1
            const short8 bh0 = *(const short8*)(bh_s + crow * KDIM + p0);
            const short8 bh1 = *(const short8*)(bh_s + crow * KDIM + p1);
            const short8 bl0 = *(const short8*)(bl_s + crow * KDIM + p0);
            const short8 bl1 = *(const short8*)(bl_s + crow * KDIM + p1);
            const int code = ch * CHUNK + crow;

            #pragma unroll
            for (int t = 0; t < 2; ++t) {
                // three INDEPENDENT 2-deep chains (hh, lh, hl split terms)
                f32x4 va = {nv, nv, nv, nv};
                f32x4 vb = {0.f, 0.f, 0.f, 0.f};
                f32x4 vc = {0.f, 0.f, 0.f, 0.f};
                va = __builtin_amdgcn_mfma_f32_16x16x32_bf16(ah[t][0], bh0, va, 0, 0, 0);
                vb = __builtin_amdgcn_mfma_f32_16x16x32_bf16(al[t][0], bh0, vb, 0, 0, 0);
                vc = __builtin_amdgcn_mfma_f32_16x16x32_bf16(ah[t][0], bl0, vc, 0, 0, 0);
                va = __builtin_amdgcn_mfma_f32_16x16x32_bf16(ah[t][1], bh1, va, 0, 0, 0);
                vb = __builtin_amdgcn_mfma_f32_16x16x32_bf16(al[t][1], bh1, vb, 0, 0, 0);
                vc = __builtin_amdgcn_mfma_f32_16x16x32_bf16(ah[t][1], bl1, vc, 0, 0, 0);
                #pragma unroll
                for (int r = 0; r < 4; ++r) {   // query m=quad*4+r, code n=code
                    float d = (va[r] + vb[r]) + vc[r];
                    bool c = d < m1[t][r];
                    m2[t][r] = __builtin_amdgcn_fmed3f(d, m1[t][r], m2[t][r]);
                    m1[t][r] = fminf(m1[t][r], d);
                    i1[t][r] = c ? code : i1[t][r];
                }
            }
        }
    }

    // ---- merge across 16 lanes (code residues), first-index ties
    #pragma unroll
    for (int s = 1; s < 16; s <<= 1)
        #pragma unroll
        for (int t = 0; t < 2; ++t)
            #pragma unroll
            for (int r = 0; r < 4; ++r) {
                float o1 = __shfl_xor(m1[t][r], s, 64);
                int   oi = __shfl_xor(i1[t][r], s, 64);
                float o2 = __shfl_xor(m2[t][r], s, 64);
                m2[t][r] = __builtin_amdgcn_fmed3f(m1[t][r], o1, fminf(m2[t][r], o2));
                if (o1 < m1[t][r] || (o1 == m1[t][r] && oi < i1[t][r])) {
                    m1[t][r] = o1; i1[t][r] = oi;
                }
            }

    // ---- owners (l16==0): publish idx, flags, loss partial
    float lsum = 0.0f;
    if (l16 == 0) {
        #pragma unroll
        for (int t = 0; t < 2; ++t)
            #pragma unroll
            for (int r = 0; r < 4; ++r) {
                const int ql = 32 * w + t * 16 + quad * 4 + r;
                idx_s[ql] = i1[t][r];
                lsum += m1[t][r] + zn_s[ql];
                if (m2[t][r] - m1[t][r] < TAU) {
                    int pos = atomicAdd(flag_cnt, 1);
                    if (pos < FCAP) {
                        flag_q[pos]   = qb + ql;
                        flag_m1[pos]  = m1[t][r];
                        flag_idx[pos] = i1[t][r];
                    }
                }
            }
    }
    #pragma unroll
    for (int s = 1; s < 64; s <<= 1) lsum += __shfl_xor(lsum, s, 64);
    if (lane == 0) atomicAdd(loss_acc, lsum);
    __syncthreads();

    // ---- epilogue: thread -> (query tid&127, channels [32*(tid>>7),+32))
    {
        const int q   = tid & 127;
        const int cs  = (tid >> 7) * 32;
        const int idx = idx_s[q];
        const float4* row = (const float4*)(cb + (size_t)idx * KDIM + cs);
        float* op = out + 1 + (size_t)b * CHW + (size_t)cs * HWD + hw0 + q;
        #pragma unroll
        for (int i4 = 0; i4 < 8; ++i4) {
            float4 v = row[i4];
            op[(size_t)(i4 * 4 + 0) * HWD] = v.x;
            op[(size_t)(i4 * 4 + 1) * HWD] = v.y;
            op[(size_t)(i4 * 4 + 2) * HWD] = v.z;
            op[(size_t)(i4 * 4 + 3) * HWD] = v.w;
        }
    }
}

// ---------------- fix: exact fp32 re-rank for flagged queries + finalize ----
__global__ void vq_fix(const float* __restrict__ z,
                       const float* __restrict__ cb,
                       float* __restrict__ out,
                       float* __restrict__ loss_acc,
                       const int* __restrict__ flag_q,
                       const float* __restrict__ flag_m1,
                       const int* __restrict__ flag_idx,
                       const int* __restrict__ flag_cnt,
                       int* __restrict__ done_cnt) {
    const int w    = threadIdx.x >> 6;
    const int lane = threadIdx.x & 63;
    const int gw   = blockIdx.x * 4 + w;
    const int NW   = gridDim.x * 4;

    int n = *flag_cnt;
    if (n > FCAP) n = FCAP;

    for (int f = gw; f < n; f += NW) {
        const int   q   = flag_q[f];
        const float m1o = flag_m1[f];
        const int   io  = flag_idx[f];
        const int   b   = q >> 12;
        const int   hw  = q & 4095;

        float zv[KDIM];
        float znorm = 0.0f;
        #pragma unroll
        for (int k = 0; k < KDIM; ++k) {
            zv[k] = z[(size_t)b * CHW + (size_t)k * HWD + hw];
            znorm = fmaf(zv[k], zv[k], znorm);
        }
        float best = 3.4e38f; int bj = 0;
        for (int i = 0; i < 16; ++i) {
            const int j = lane * 16 + i;
            const float4* row = (const float4*)(cb + (size_t)j * KDIM);
            float d = 0.0f;
            #pragma unroll
            for (int k4 = 0; k4 < 16; ++k4) {
                float4 v = row[k4];
                float t0 = zv[k4 * 4 + 0] - v.x;
                float t1 = zv[k4 * 4 + 1] - v.y;
                float t2 = zv[k4 * 4 + 2] - v.z;
                float t3 = zv[k4 * 4 + 3] - v.w;
                d = fmaf(t0, t0, d); d = fmaf(t1, t1, d);
                d = fmaf(t2, t2, d); d = fmaf(t3, t3, d);
            }
            if (d < best) { best = d; bj = j; }
        }
        #pragma unroll
        for (int s = 1; s < 64; s <<= 1) {
            float ob = __shfl_xor(best, s, 64);
            int   oj = __shfl_xor(bj, s, 64);
            if (ob < best || (ob == best && oj < bj)) { best = ob; bj = oj; }
        }
        if (bj != io) {
            out[1 + (size_t)b * CHW + (size_t)lane * HWD + hw] = cb[(size_t)bj * KDIM + lane];
            if (lane == 0) atomicAdd(loss_acc, best - (m1o + znorm));
        }
    }

    __syncthreads();
    if (threadIdx.x == 0) {
        __threadfence();
        int old = atomicAdd(done_cnt, 1);
        if (old == (int)gridDim.x - 1) {
            float L = atomicAdd(loss_acc, 0.0f);
            out[0] = 1.25f * L / TOTALF;
        }
    }
}

extern "C" void kernel_launch(void* const* d_in, const int* in_sizes, int n_in,
                              void* d_out, int out_size, void* d_ws, size_t ws_size,
                              hipStream_t stream) {
    const float* z  = (const float*)d_in[0];
    const float* cb = (const float*)d_in[1];
    float* out      = (float*)d_out;
    char*  ws       = (char*)d_ws;

    float*          loss_acc = (float*)(ws + 0);
    int*            flag_cnt = (int*)(ws + 4);
    int*            done_cnt = (int*)(ws + 8);
    float*          norms    = (float*)(ws + 128);
    unsigned short* cbh      = (unsigned short*)(ws + 4224);
    unsigned short* cbl      = (unsigned short*)(ws + 135296);
    int*            flag_q   = (int*)(ws + 266368);
    float*          flag_m1  = (float*)(ws + 331904);
    int*            flag_idx = (int*)(ws + 397440);

    vq_prep<<<dim3(16), dim3(256), 0, stream>>>(cb, norms, cbh, cbl,
                                                loss_acc, flag_cnt, done_cnt);

    vq_main<<<dim3(NQ / 128), dim3(256), 0, stream>>>(z, cb, cbh, cbl, norms, out,
                                                      loss_acc, flag_q, flag_m1,
                                                      flag_idx, flag_cnt);

    vq_fix<<<dim3(256), dim3(256), 0, stream>>>(z, cb, out, loss_acc,
                                                flag_q, flag_m1, flag_idx,
                                                flag_cnt, done_cnt);
}

// Round 8
// 200.793 us; speedup vs baseline: 1.8388x; 1.8388x over previous
//
#include <hip/hip_runtime.h>

// VQ-VAE VectorQuantizer: bf16 split-MFMA distance + exact fp32 fallback.
// z: (32,64,64,64) NCHW fp32; codebook: (1024,64) fp32.
// d_out: [0]=loss, [1..]=z_q (NCHW).
//
// R8 (from R6 base; R7's 3-way acc split spilled -> 670MB scratch traffic):
// double-banked accumulators + DEFERRED tracking. Tile k's MFMAs write bank
// k&1; its accvgpr_read + min-track runs during tile k+1 (other bank). This
// breaks the acc WAR recycling that serialized R6's tiles into ~500-1000cyc
// round-trips (MfmaUtil pinned ~20% across all occupancies). Only +8 AGPR
// vs R6 (4 live f32x4, not R7's 6).

#define CB_N   1024
#define KDIM   64
#define HWD    4096
#define CHW    (KDIM * HWD)
#define NQ     131072
#define TOTALF 8388608.0f
#define TAU    2.5e-4f
#define FCAP   16384
#define CHUNK  128            // codes per LDS chunk
#define NCHUNK (CB_N / CHUNK)

typedef __attribute__((ext_vector_type(8))) short  short8;
typedef __attribute__((ext_vector_type(4))) float  f32x4;

__device__ __forceinline__ unsigned short bf16_rne(float f) {
    union { float f; unsigned u; } c; c.f = f;
    return (unsigned short)((c.u + 0x7FFFu + ((c.u >> 16) & 1u)) >> 16);
}
__device__ __forceinline__ float bf16_tof(unsigned short h) {
    union { unsigned u; float f; } c; c.u = ((unsigned)h) << 16; return c.f;
}

// async 16B/lane global->LDS copy (wave-uniform contiguous; m97 pattern)
__device__ __forceinline__ void gload_lds16(const void* g, void* l) {
    __builtin_amdgcn_global_load_lds(
        (const __attribute__((address_space(1))) unsigned int*)g,
        (__attribute__((address_space(3))) unsigned int*)l,
        16, 0, 0);
}

// ---------- ws layout (byte offsets) ----------
// 0: loss_acc  4: flag_cnt  8: done_cnt
// 128:    norms   f32[1024]
// 4224:   cbh_sw  u16[1024*64]   (XOR-swizzled rows)
// 135296: cbl_sw  u16[1024*64]
// 266368: flag_q i32[FCAP]  331904: flag_m1 f32[FCAP]  397440: flag_idx i32[FCAP]

// ---------------- prep: bf16 hi/lo split, swizzled rows, norms, counters ----
__global__ void vq_prep(const float* __restrict__ cb,
                        float* __restrict__ norms,
                        unsigned short* __restrict__ cbh,
                        unsigned short* __restrict__ cbl,
                        float* __restrict__ loss_acc,
                        int* __restrict__ flag_cnt,
                        int* __restrict__ done_cnt) {
    const int tid = blockIdx.x * 256 + threadIdx.x;
    if (tid == 0) *loss_acc = 0.0f;
    if (tid == 1) *flag_cnt = 0;
    if (tid == 2) *done_cnt = 0;
    const int j  = tid >> 2;
    const int s2 = tid & 3;

    const float4* r4 = (const float4*)(cb + (size_t)j * KDIM);
    float s_norm = 0.0f;
    #pragma unroll
    for (int seg8 = 0; seg8 < 2; ++seg8) {
        const int s = s2 * 2 + seg8;
        float4 v0 = r4[s * 2 + 0];
        float4 v1 = r4[s * 2 + 1];
        float e[8] = {v0.x, v0.y, v0.z, v0.w, v1.x, v1.y, v1.z, v1.w};
        unsigned hh[4], ll[4];
        #pragma unroll
        for (int c = 0; c < 8; ++c) {
            float x = e[c];
            s_norm = fmaf(x, x, s_norm);
            unsigned short h = bf16_rne(x);
            unsigned short l = bf16_rne(x - bf16_tof(h));
            if ((c & 1) == 0) { hh[c >> 1] = h; ll[c >> 1] = l; }
            else { hh[c >> 1] |= ((unsigned)h) << 16; ll[c >> 1] |= ((unsigned)l) << 16; }
        }
        const int p = (s + j) & 7;
        *(uint4*)(cbh + (size_t)j * KDIM + p * 8) = make_uint4(hh[0], hh[1], hh[2], hh[3]);
        *(uint4*)(cbl + (size_t)j * KDIM + p * 8) = make_uint4(ll[0], ll[1], ll[2], ll[3]);
    }
    s_norm += __shfl_xor(s_norm, 1, 64);
    s_norm += __shfl_xor(s_norm, 2, 64);
    if (s2 == 0) norms[j] = s_norm;
}

// ---------------- main ------------------------------------------------------
__global__ __launch_bounds__(256, 3) void vq_main(
        const float* __restrict__ z,
        const float* __restrict__ cb,
        const unsigned short* __restrict__ cbh,
        const unsigned short* __restrict__ cbl,
        const float* __restrict__ norms,
        float* __restrict__ out,
        float* __restrict__ loss_acc,
        int* __restrict__ flag_q,
        float* __restrict__ flag_m1,
        int* __restrict__ flag_idx,
        int* __restrict__ flag_cnt) {
    __shared__ float          norms_s[CB_N];            // 4 KB
    __shared__ unsigned short bh_s[CHUNK * KDIM];       // 16 KB
    __shared__ unsigned short bl_s[CHUNK * KDIM];       // 16 KB
    __shared__ float          zn_s[128];
    __shared__ int            idx_s[128];

    const int tid  = threadIdx.x;
    const int w    = tid >> 6;
    const int lane = tid & 63;
    const int quad = lane >> 4;
    const int l16  = lane & 15;
    const int qb   = blockIdx.x * 128;     // block's 128 queries (same batch b)
    const int b    = qb >> 12;
    const int hw0  = qb & 4095;
    const int ch0  = blockIdx.x & (NCHUNK - 1);   // de-phase chunk start

    // ---- stage all code norms into LDS
    *(float4*)(norms_s + tid * 4) = *(const float4*)(norms + tid * 4);

    // ---- stage A-frags: wave w owns queries [32w, 32w+32); 2 tiles of 16.
    const float* zbase = z + (size_t)b * CHW + hw0 + 32 * w;
    short8 ah[2][2], al[2][2];
    float znp[2] = {0.f, 0.f};
    #pragma unroll
    for (int t = 0; t < 2; ++t)
        #pragma unroll
        for (int ks = 0; ks < 2; ++ks)
            #pragma unroll
            for (int j = 0; j < 8; ++j) {
                float v = zbase[(size_t)(ks * 32 + quad * 8 + j) * HWD + t * 16 + l16];
                znp[t] = fmaf(v, v, znp[t]);
                float s = -2.0f * v;
                unsigned short h = bf16_rne(s);
                ah[t][ks][j] = (short)h;
                al[t][ks][j] = (short)bf16_rne(s - bf16_tof(h));
            }
    #pragma unroll
    for (int t = 0; t < 2; ++t) {
        znp[t] += __shfl_xor(znp[t], 16, 64);
        znp[t] += __shfl_xor(znp[t], 32, 64);
    }
    if (lane < 16) {
        zn_s[32 * w + lane]      = znp[0];
        zn_s[32 * w + 16 + lane] = znp[1];
    }

    // ---- chunk loop (round-robin from ch0): async-stage 128 codes, 8 n-tiles
    float m1[2][4], m2[2][4];
    int   i1[2][4];
    #pragma unroll
    for (int t = 0; t < 2; ++t)
        #pragma unroll
        for (int r = 0; r < 4; ++r) { m1[t][r] = 3.4e38f; m2[t][r] = 3.4e38f; i1[t][r] = 0; }

    // loop-invariant swizzled segment offsets (ks=0 / ks=1)
    const int p0 = ((quad + l16) & 7) * 8;
    const int p1 = ((4 + quad + l16) & 7) * 8;

    f32x4 bank[2][2];               // [bank][t] -- double-banked accumulators
    bank[0][0] = bank[0][1] = (f32x4){0.f, 0.f, 0.f, 0.f};
    bank[1][0] = bank[1][1] = (f32x4){0.f, 0.f, 0.f, 0.f};
    int prevCode = 0;

    for (int cc = 0; cc < NCHUNK; ++cc) {
        const int ch = (cc + ch0) & (NCHUNK - 1);
        if (cc) __syncthreads();           // previous chunk's LDS reads done
        {
            const char* gh = (const char*)cbh + (size_t)ch * CHUNK * KDIM * 2;
            const char* gl = (const char*)cbl + (size_t)ch * CHUNK * KDIM * 2;
            #pragma unroll
            for (int i = 0; i < 4; ++i) {
                const int off = (w * 4 + i) * 1024 + lane * 16;
                gload_lds16(gh + off, (char*)bh_s + off);
                gload_lds16(gl + off, (char*)bl_s + off);
            }
        }
        __syncthreads();                   // drains vmcnt -> LDS valid

        #pragma unroll
        for (int t8 = 0; t8 < 8; ++t8) {
            const int crow = t8 * 16 + l16;            // chunk-local code row
            const float nv = norms_s[ch * CHUNK + crow];
            const short8 bh0 = *(const short8*)(bh_s + crow * KDIM + p0);
            const short8 bh1 = *(const short8*)(bh_s + crow * KDIM + p1);
            const short8 bl0 = *(const short8*)(bl_s + crow * KDIM + p0);
            const short8 bl1 = *(const short8*)(bl_s + crow * KDIM + p1);
            const int code = ch * CHUNK + crow;
            const int cur = t8 & 1, prv = cur ^ 1;

            // track the DEFERRED tile (previous t8) held in bank[prv];
            // independent of bank[cur]'s MFMAs below -> overlaps them
            if (cc + t8 > 0) {
                #pragma unroll
                for (int t = 0; t < 2; ++t)
                    #pragma unroll
                    for (int r = 0; r < 4; ++r) {
                        float d = bank[prv][t][r];
                        bool cnd = d < m1[t][r];
                        m2[t][r] = __builtin_amdgcn_fmed3f(d, m1[t][r], m2[t][r]);
                        m1[t][r] = fminf(m1[t][r], d);
                        i1[t][r] = cnd ? prevCode : i1[t][r];
                    }
            }

            #pragma unroll
            for (int t = 0; t < 2; ++t) {
                f32x4 acc = {nv, nv, nv, nv};
                acc = __builtin_amdgcn_mfma_f32_16x16x32_bf16(ah[t][0], bh0, acc, 0, 0, 0);
                acc = __builtin_amdgcn_mfma_f32_16x16x32_bf16(al[t][0], bh0, acc, 0, 0, 0);
                acc = __builtin_amdgcn_mfma_f32_16x16x32_bf16(ah[t][0], bl0, acc, 0, 0, 0);
                acc = __builtin_amdgcn_mfma_f32_16x16x32_bf16(ah[t][1], bh1, acc, 0, 0, 0);
                acc = __builtin_amdgcn_mfma_f32_16x16x32_bf16(al[t][1], bh1, acc, 0, 0, 0);
                acc = __builtin_amdgcn_mfma_f32_16x16x32_bf16(ah[t][1], bl1, acc, 0, 0, 0);
                bank[cur][t] = acc;
            }
            prevCode = code;
        }
    }
    // final deferred tile (last t8=7 wrote bank[1])
    {
        #pragma unroll
        for (int t = 0; t < 2; ++t)
            #pragma unroll
            for (int r = 0; r < 4; ++r) {
                float d = bank[1][t][r];
                bool cnd = d < m1[t][r];
                m2[t][r] = __builtin_amdgcn_fmed3f(d, m1[t][r], m2[t][r]);
                m1[t][r] = fminf(m1[t][r], d);
                i1[t][r] = cnd ? prevCode : i1[t][r];
            }
    }

    // ---- merge across 16 lanes (code residues), first-index ties
    #pragma unroll
    for (int s = 1; s < 16; s <<= 1)
        #pragma unroll
        for (int t = 0; t < 2; ++t)
            #pragma unroll
            for (int r = 0; r < 4; ++r) {
                float o1 = __shfl_xor(m1[t][r], s, 64);
                int   oi = __shfl_xor(i1[t][r], s, 64);
                float o2 = __shfl_xor(m2[t][r], s, 64);
                m2[t][r] = __builtin_amdgcn_fmed3f(m1[t][r], o1, fminf(m2[t][r], o2));
                if (o1 < m1[t][r] || (o1 == m1[t][r] && oi < i1[t][r])) {
                    m1[t][r] = o1; i1[t][r] = oi;
                }
            }

    // ---- owners (l16==0): publish idx, flags, loss partial
    float lsum = 0.0f;
    if (l16 == 0) {
        #pragma unroll
        for (int t = 0; t < 2; ++t)
            #pragma unroll
            for (int r = 0; r < 4; ++r) {
                const int ql = 32 * w + t * 16 + quad * 4 + r;
                idx_s[ql] = i1[t][r];
                lsum += m1[t][r] + zn_s[ql];
                if (m2[t][r] - m1[t][r] < TAU) {
                    int pos = atomicAdd(flag_cnt, 1);
                    if (pos < FCAP) {
                        flag_q[pos]   = qb + ql;
                        flag_m1[pos]  = m1[t][r];
                        flag_idx[pos] = i1[t][r];
                    }
                }
            }
    }
    #pragma unroll
    for (int s = 1; s < 64; s <<= 1) lsum += __shfl_xor(lsum, s, 64);
    if (lane == 0) atomicAdd(loss_acc, lsum);
    __syncthreads();

    // ---- epilogue: thread -> (query tid&127, channels [32*(tid>>7),+32))
    {
        const int q   = tid & 127;
        const int cs  = (tid >> 7) * 32;
        const int idx = idx_s[q];
        const float4* row = (const float4*)(cb + (size_t)idx * KDIM + cs);
        float* op = out + 1 + (size_t)b * CHW + (size_t)cs * HWD + hw0 + q;
        #pragma unroll
        for (int i4 = 0; i4 < 8; ++i4) {
            float4 v = row[i4];
            op[(size_t)(i4 * 4 + 0) * HWD] = v.x;
            op[(size_t)(i4 * 4 + 1) * HWD] = v.y;
            op[(size_t)(i4 * 4 + 2) * HWD] = v.z;
            op[(size_t)(i4 * 4 + 3) * HWD] = v.w;
        }
    }
}

// ---------------- fix: exact fp32 re-rank for flagged queries + finalize ----
__global__ void vq_fix(const float* __restrict__ z,
                       const float* __restrict__ cb,
                       float* __restrict__ out,
                       float* __restrict__ loss_acc,
                       const int* __restrict__ flag_q,
                       const float* __restrict__ flag_m1,
                       const int* __restrict__ flag_idx,
                       const int* __restrict__ flag_cnt,
                       int* __restrict__ done_cnt) {
    const int w    = threadIdx.x >> 6;
    const int lane = threadIdx.x & 63;
    const int gw   = blockIdx.x * 4 + w;
    const int NW   = gridDim.x * 4;

    int n = *flag_cnt;
    if (n > FCAP) n = FCAP;

    for (int f = gw; f < n; f += NW) {
        const int   q   = flag_q[f];
        const float m1o = flag_m1[f];
        const int   io  = flag_idx[f];
        const int   b   = q >> 12;
        const int   hw  = q & 4095;

        float zv[KDIM];
        float znorm = 0.0f;
        #pragma unroll
        for (int k = 0; k < KDIM; ++k) {
            zv[k] = z[(size_t)b * CHW + (size_t)k * HWD + hw];
            znorm = fmaf(zv[k], zv[k], znorm);
        }
        float best = 3.4e38f; int bj = 0;
        for (int i = 0; i < 16; ++i) {
            const int j = lane * 16 + i;
            const float4* row = (const float4*)(cb + (size_t)j * KDIM);
            float d = 0.0f;
            #pragma unroll
            for (int k4 = 0; k4 < 16; ++k4) {
                float4 v = row[k4];
                float t0 = zv[k4 * 4 + 0] - v.x;
                float t1 = zv[k4 * 4 + 1] - v.y;
                float t2 = zv[k4 * 4 + 2] - v.z;
                float t3 = zv[k4 * 4 + 3] - v.w;
                d = fmaf(t0, t0, d); d = fmaf(t1, t1, d);
                d = fmaf(t2, t2, d); d = fmaf(t3, t3, d);
            }
            if (d < best) { best = d; bj = j; }
        }
        #pragma unroll
        for (int s = 1; s < 64; s <<= 1) {
            float ob = __shfl_xor(best, s, 64);
            int   oj = __shfl_xor(bj, s, 64);
            if (ob < best || (ob == best && oj < bj)) { best = ob; bj = oj; }
        }
        if (bj != io) {
            out[1 + (size_t)b * CHW + (size_t)lane * HWD + hw] = cb[(size_t)bj * KDIM + lane];
            if (lane == 0) atomicAdd(loss_acc, best - (m1o + znorm));
        }
    }

    __syncthreads();
    if (threadIdx.x == 0) {
        __threadfence();
        int old = atomicAdd(done_cnt, 1);
        if (old == (int)gridDim.x - 1) {
            float L = atomicAdd(loss_acc, 0.0f);
            out[0] = 1.25f * L / TOTALF;
        }
    }
}

extern "C" void kernel_launch(void* const* d_in, const int* in_sizes, int n_in,
                              void* d_out, int out_size, void* d_ws, size_t ws_size,
                              hipStream_t stream) {
    const float* z  = (const float*)d_in[0];
    const float* cb = (const float*)d_in[1];
    float* out      = (float*)d_out;
    char*  ws       = (char*)d_ws;

    float*          loss_acc = (float*)(ws + 0);
    int*            flag_cnt = (int*)(ws + 4);
    int*            done_cnt = (int*)(ws + 8);
    float*          norms    = (float*)(ws + 128);
    unsigned short* cbh      = (unsigned short*)(ws + 4224);
    unsigned short* cbl      = (unsigned short*)(ws + 135296);
    int*            flag_q   = (int*)(ws + 266368);
    float*          flag_m1  = (float*)(ws + 331904);
    int*            flag_idx = (int*)(ws + 397440);

    vq_prep<<<dim3(16), dim3(256), 0, stream>>>(cb, norms, cbh, cbl,
                                                loss_acc, flag_cnt, done_cnt);

    vq_main<<<dim3(NQ / 128), dim3(256), 0, stream>>>(z, cb, cbh, cbl, norms, out,
                                                      loss_acc, flag_q, flag_m1,
                                                      flag_idx, flag_cnt);

    vq_fix<<<dim3(256), dim3(256), 0, stream>>>(z, cb, out, loss_acc,
                                                flag_q, flag_m1, flag_idx,
                                                flag_cnt, done_cnt);
}